// Round 12
// baseline (243.756 us; speedup 1.0000x reference)
//
#include <hip/hip_runtime.h>

#define N_NODES  100000
#define N_EDGES  3200000
#define N_GRAPHS 1000

#define NPB      128                                  // nodes per bucket (pow2)
#define NB       782                                  // ceil(N_NODES/NPB)
#define CAPL     4608                                 // LDS sort cap: mean 4092 + 8 sigma

typedef float    f32x4 __attribute__((ext_vector_type(4)));
typedef unsigned u32x4 __attribute__((ext_vector_type(4)));

// ---------------- fat-path ws layout (bytes) ----------------
#define HIST_OFF   0                                  // u32 hist[NB]
#define BASE_OFF   4096                               // u32 base[NB+1]
#define CUR_OFF    8192                               // u32 cursor[NB]
#define G_OFF      12288                              // f32 g[5000]
#define ZERO_BYTES 32768                              // memset [0, ZERO_BYTES)
#define P_OFF      32768                              // u32 P[N_NODES][8] f16-packed = 3.2 MB
#define ENT_OFF    4832768                            // 32B entries [3.2M]
#define WS_FAT     (ENT_OFF + (size_t)N_EDGES * 32)   // ~107 MB

// scatter config: 512 blocks (2/CU), 6250 edges each (512*6250 = 3.2M exactly)
#define S_T      1024
#define S_GRID   512
#define S_E      6250
#define S_K      7                                    // ceil(S_E / S_T)
#define BK_T     1024

// ---------------- legacy (round-5) ws layout ----------------
#define L_CAP      4500
#define L_OVF_CAP  16384
#define L_BLK_E    8192
#define L_S1_GRID  ((N_EDGES + L_BLK_E - 1) / L_BLK_E)
#define L_CUR_OFF    0
#define L_OVFC_OFF   4096
#define L_G_OFF      4352
#define L_ZERO_BYTES 24576
#define L_OVF_OFF    24576
#define L_SORT_OFF   163840
#define L_WS_NEED    (L_SORT_OFF + (size_t)NB * L_CAP * 8)

__device__ __forceinline__ float fast_tanh(float x) {
    float e = __expf(2.0f * x);
    return 1.0f - 2.0f * __builtin_amdgcn_rcpf(e + 1.0f);
}

// f16 pack/unpack (RTNE via _Float16 casts)
__device__ __forceinline__ unsigned pkh(float a, float b) {
    union { _Float16 h[2]; unsigned u; } c;
    c.h[0] = (_Float16)a; c.h[1] = (_Float16)b;
    return c.u;
}
__device__ __forceinline__ void upkh(unsigned u, float& a, float& b) {
    union { unsigned u; _Float16 h[2]; } c;
    c.u = u;
    a = (float)c.h[0]; b = (float)c.h[1];
}

// ============================================================
//                      FAT PATH
// ============================================================

// ---- histogram of dst>>7 ----
__global__ __launch_bounds__(1024) void hist_kernel(
    const int* __restrict__ ei, unsigned* __restrict__ hist)
{
    __shared__ unsigned lh[NB];
    const int tid = threadIdx.x;
    for (int b = tid; b < NB; b += 1024) lh[b] = 0u;
    __syncthreads();
    for (int e = blockIdx.x * 1024 + tid; e < N_EDGES; e += gridDim.x * 1024) {
        int d = __builtin_nontemporal_load(ei + N_EDGES + e);
        atomicAdd(&lh[d >> 7], 1u);
    }
    __syncthreads();
    for (int b = tid; b < NB; b += 1024)
        if (lh[b]) atomicAdd(hist + b, lh[b]);
}

// ---- exclusive scan over NB bins (1 block) ----
__global__ __launch_bounds__(1024) void scan_kernel(
    const unsigned* __restrict__ hist,
    unsigned* __restrict__ base, unsigned* __restrict__ cursor)
{
    __shared__ unsigned A[NB];
    const int i = threadIdx.x;
    unsigned h0 = 0;
    if (i < NB) { h0 = hist[i]; A[i] = h0; }
    __syncthreads();
    #pragma unroll
    for (int off = 1; off < NB; off <<= 1) {
        unsigned t = 0;
        if (i < NB && i >= off) t = A[i - off];
        __syncthreads();
        if (i < NB) A[i] += t;
        __syncthreads();
    }
    if (i < NB) {
        unsigned excl = A[i] - h0;
        base[i] = excl;
        cursor[i] = excl;
        if (i == NB - 1) base[NB] = A[i];
    }
}

// ---- node projection: P[n] = f16-packed node_attr[n] @ Wm rows 0..15 ----
__global__ __launch_bounds__(256) void nodeproj_kernel(
    const float* __restrict__ node_attr, const float* __restrict__ Wm,
    unsigned* __restrict__ P)
{
    int n = blockIdx.x * 256 + threadIdx.x;
    if (n >= N_NODES) return;
    float r[16];
    const f32x4* na = reinterpret_cast<const f32x4*>(node_attr + (size_t)n * 16);
    #pragma unroll
    for (int q = 0; q < 4; ++q) {
        f32x4 v = na[q];
        r[q*4+0] = v.x; r[q*4+1] = v.y; r[q*4+2] = v.z; r[q*4+3] = v.w;
    }
    float p[10];
    #pragma unroll
    for (int j = 0; j < 10; ++j) p[j] = 0.0f;
    #pragma unroll
    for (int i = 0; i < 16; ++i) {
        float xi = r[i];
        #pragma unroll
        for (int j = 0; j < 10; ++j) p[j] = fmaf(xi, Wm[i*10 + j], p[j]);
    }
    u32x4* pd = reinterpret_cast<u32x4*>(P + (size_t)n * 8);
    u32x4 w0 = {pkh(p[0],p[1]), pkh(p[2],p[3]), pkh(p[4],p[5]), pkh(p[6],p[7])};
    u32x4 w1 = {pkh(p[8],p[9]), 0u, 0u, 0u};
    pd[0] = w0; pd[1] = w1;
}

// ---- scatter: rank captured in count pass; slot precomputed into registers;
//      main loop has ZERO LDS ops; pipelined loads; 32B f16 entries ----
__global__ __launch_bounds__(S_T, 4) void scatter_msg_kernel(
    const int* __restrict__ ei, const float* __restrict__ edge_attr,
    const unsigned* __restrict__ P,
    const float* __restrict__ Wm, const float* __restrict__ bm,
    unsigned* __restrict__ cursor, unsigned* __restrict__ entries)
{
    __shared__ unsigned lh[NB];
    __shared__ unsigned lb[NB];
    const int tid  = threadIdx.x;
    const int e0   = blockIdx.x * S_E;
    const int e1   = e0 + S_E;                         // exact (512*6250 = E)
    const int last = e1 - 1;

    for (int b = tid; b < NB; b += S_T) lh[b] = 0u;
    __syncthreads();

    // count pass: capture local RANK per edge (atomic return value)
    int dch[S_K];
    unsigned rch[S_K];
    #pragma unroll
    for (int k = 0; k < S_K; ++k) {
        int e = e0 + k * S_T + tid;
        int d = (e < e1) ? __builtin_nontemporal_load(ei + N_EDGES + e) : -1;
        dch[k] = d;
        rch[k] = (d >= 0) ? atomicAdd(&lh[d >> 7], 1u) : 0u;
    }
    __syncthreads();

    for (int b = tid; b < NB; b += S_T) {
        unsigned c = lh[b];
        lb[b] = c ? atomicAdd(cursor + b, c) : 0u;     // contiguous run per (block,bucket)
    }
    __syncthreads();

    // precompute packed (slot<<7 | dl) per iteration — frees the main loop
    // from ALL LDS traffic
    unsigned mch[S_K];
    #pragma unroll
    for (int k = 0; k < S_K; ++k) {
        int d = dch[k];
        mch[k] = (d >= 0) ? (((lb[d >> 7] + rch[k]) << 7) | (unsigned)(d & 127))
                          : 0xFFFFFFFFu;
    }

    const int eBase = e0 + tid;
    #define ECL(x) ((x) > last ? last : (x))

    // ---- pipeline prologue ----
    int sA = __builtin_nontemporal_load(ei + ECL(eBase));          // src k=0
    int sB = __builtin_nontemporal_load(ei + ECL(eBase + S_T));    // src k=1
    f32x4 rA0, rA1, rA2, rA3;                                      // edge_attr k=0
    {
        const f32x4* ea = reinterpret_cast<const f32x4*>(edge_attr + (size_t)ECL(eBase) * 16);
        rA0 = __builtin_nontemporal_load(ea + 0);
        rA1 = __builtin_nontemporal_load(ea + 1);
        rA2 = __builtin_nontemporal_load(ea + 2);
        rA3 = __builtin_nontemporal_load(ea + 3);
    }
    u32x4 pA; unsigned pA4;                                        // P k=0 (waits sA)
    {
        const u32x4* pp = reinterpret_cast<const u32x4*>(P + (size_t)sA * 8);
        pA = pp[0]; pA4 = P[(size_t)sA * 8 + 4];
    }

    #pragma unroll
    for (int k = 0; k < S_K; ++k) {
        const int e = eBase + k * S_T;

        // issue src k+2
        int sC = 0;
        if (k + 2 < S_K) sC = __builtin_nontemporal_load(ei + ECL(e + 2 * S_T));

        // issue edge_attr k+1
        f32x4 rB0 = rA0, rB1 = rA1, rB2 = rA2, rB3 = rA3;
        if (k + 1 < S_K) {
            const f32x4* ea = reinterpret_cast<const f32x4*>(edge_attr + (size_t)ECL(e + S_T) * 16);
            rB0 = __builtin_nontemporal_load(ea + 0);
            rB1 = __builtin_nontemporal_load(ea + 1);
            rB2 = __builtin_nontemporal_load(ea + 2);
            rB3 = __builtin_nontemporal_load(ea + 3);
        }
        // issue P k+1 (sB already in flight for 1 iter)
        u32x4 pB = pA; unsigned pB4 = pA4;
        if (k + 1 < S_K) {
            const u32x4* pp = reinterpret_cast<const u32x4*>(P + (size_t)sB * 8);
            pB = pp[0]; pB4 = P[(size_t)sB * 8 + 4];
        }

        // compute + store for iteration k (address from registers only)
        const unsigned mc = mch[k];
        if (mc != 0xFFFFFFFFu) {
            float r[16];
            r[0]=rA0.x; r[1]=rA0.y; r[2]=rA0.z; r[3]=rA0.w;
            r[4]=rA1.x; r[5]=rA1.y; r[6]=rA1.z; r[7]=rA1.w;
            r[8]=rA2.x; r[9]=rA2.y; r[10]=rA2.z; r[11]=rA2.w;
            r[12]=rA3.x; r[13]=rA3.y; r[14]=rA3.z; r[15]=rA3.w;

            float B[10];
            #pragma unroll
            for (int j = 0; j < 10; ++j) B[j] = bm[j];
            #pragma unroll
            for (int i = 0; i < 16; ++i) {
                float xi = r[i];
                #pragma unroll
                for (int j = 0; j < 10; ++j) B[j] = fmaf(xi, Wm[(16 + i)*10 + j], B[j]);
            }
            float Pv[10];
            upkh(pA.x, Pv[0], Pv[1]);
            upkh(pA.y, Pv[2], Pv[3]);
            upkh(pA.z, Pv[4], Pv[5]);
            upkh(pA.w, Pv[6], Pv[7]);
            upkh(pA4,  Pv[8], Pv[9]);
            float m[10];
            #pragma unroll
            for (int j = 0; j < 10; ++j) m[j] = fast_tanh(B[j] + Pv[j]);

            unsigned pos = mc >> 7;
            u32x4* ep = reinterpret_cast<u32x4*>(entries + (size_t)pos * 8);
            u32x4 w0 = {pkh(m[0],m[1]), pkh(m[2],m[3]), pkh(m[4],m[5]), pkh(m[6],m[7])};
            u32x4 w1 = {pkh(m[8],m[9]), mc & 127u, 0u, 0u};
            ep[0] = w0;                                // regular stores: combine in L2
            ep[1] = w1;
        }

        // rotate pipeline
        rA0 = rB0; rA1 = rB1; rA2 = rB2; rA3 = rB3;
        pA = pB; pA4 = pB4;
        sB = sC;
    }
    #undef ECL
}

// ---- per-bucket: counting-sort by dst-local, owner-computes register
//      segment-sum, fused node MLP + graph pooling ----
__global__ __launch_bounds__(BK_T, 8) void bucket_sort_kernel(
    const unsigned* __restrict__ entries, const unsigned* __restrict__ base,
    const int* __restrict__ batch,
    const float* __restrict__ W1, const float* __restrict__ b1,
    const float* __restrict__ W2, const float* __restrict__ b2,
    float* __restrict__ g)
{
    __shared__ unsigned seq[CAPL];                     // dl per local entry
    __shared__ unsigned ord[CAPL];                     // dl-sorted local idx
    __shared__ unsigned h[NPB], st[NPB], c2[NPB];
    __shared__ float gacc[64][5];
    __shared__ int bse[2];
    const int tid = threadIdx.x;
    const int b   = blockIdx.x;
    const unsigned lo  = base[b];
    const unsigned cnt = min(base[b + 1] - lo, (unsigned)CAPL);

    if (tid < NPB) h[tid] = 0u;
    __syncthreads();

    // phase 1: read meta, build per-node histogram + seq
    for (unsigned i = tid; i < cnt; i += BK_T) {
        unsigned dl = entries[(size_t)(lo + i) * 8 + 5] & 127u;
        seq[i] = dl;
        atomicAdd(&h[dl], 1u);
    }
    __syncthreads();

    // exclusive scan of h -> st, c2
    if (tid < NPB) st[tid] = h[tid];
    __syncthreads();
    #pragma unroll
    for (int off = 1; off < NPB; off <<= 1) {
        unsigned t = 0;
        if (tid < NPB && tid >= off) t = st[tid - off];
        __syncthreads();
        if (tid < NPB) st[tid] += t;
        __syncthreads();
    }
    if (tid < NPB) { unsigned e = st[tid] - h[tid]; st[tid] = e; c2[tid] = e; }
    __syncthreads();

    // phase 2: scatter indices into dl-sorted order
    for (unsigned i = tid; i < cnt; i += BK_T) {
        unsigned pos = atomicAdd(&c2[seq[i]], 1u);
        ord[pos] = i;
    }
    __syncthreads();

    // graph range of this block's nodes (batch sorted)
    if (tid == 0) {
        int nfirst = b * NPB;
        int nlast  = min(nfirst + NPB - 1, N_NODES - 1);
        bse[0] = batch[nfirst];
        bse[1] = batch[nlast];
    }
    __syncthreads();
    const int bmin = bse[0];
    const int R    = bse[1] - bmin + 1;
    const bool lds_pool = (R <= 64);
    if (lds_pool)
        for (int i = tid; i < R * 5; i += BK_T) ((float*)gacc)[i] = 0.0f;
    __syncthreads();

    // phase 3: owner-computes — node dl = tid>>3, slice s = tid&7
    const int dl = tid >> 3, s = tid & 7;
    float a[10];
    #pragma unroll
    for (int j = 0; j < 10; ++j) a[j] = 0.0f;
    {
        const unsigned s0 = st[dl], c = h[dl];
        for (unsigned p = s; p < c; p += 8) {
            unsigned li = ord[s0 + p];
            const u32x4* ep = reinterpret_cast<const u32x4*>(entries + (size_t)(lo + li) * 8);
            u32x4 v0 = ep[0];                          // L2-warm (phase-1 touch)
            u32x4 v1 = ep[1];
            float x0, x1;
            upkh(v0.x, x0, x1); a[0] += x0; a[1] += x1;
            upkh(v0.y, x0, x1); a[2] += x0; a[3] += x1;
            upkh(v0.z, x0, x1); a[4] += x0; a[5] += x1;
            upkh(v0.w, x0, x1); a[6] += x0; a[7] += x1;
            upkh(v1.x, x0, x1); a[8] += x0; a[9] += x1;
        }
    }
    #pragma unroll
    for (int msk = 4; msk >= 1; msk >>= 1) {
        #pragma unroll
        for (int j = 0; j < 10; ++j) a[j] += __shfl_xor(a[j], msk, 64);
    }

    const int n = b * NPB + dl;
    if (s == 0 && n < N_NODES) {
        float h1[10];
        #pragma unroll
        for (int j = 0; j < 10; ++j) h1[j] = b1[j];
        #pragma unroll
        for (int i = 0; i < 10; ++i) {
            float xi = a[i];
            #pragma unroll
            for (int j = 0; j < 10; ++j) h1[j] = fmaf(xi, W1[i*10 + j], h1[j]);
        }
        #pragma unroll
        for (int j = 0; j < 10; ++j) h1[j] = fast_tanh(h1[j]);

        float h2[5];
        #pragma unroll
        for (int j = 0; j < 5; ++j) h2[j] = b2[j];
        #pragma unroll
        for (int i = 0; i < 10; ++i) {
            float xi = h1[i];
            #pragma unroll
            for (int j = 0; j < 5; ++j) h2[j] = fmaf(xi, W2[i*5 + j], h2[j]);
        }

        const int bg = batch[n];
        if (lds_pool) {
            #pragma unroll
            for (int j = 0; j < 5; ++j) atomicAdd(&gacc[bg - bmin][j], fast_tanh(h2[j]));
        } else {
            #pragma unroll
            for (int j = 0; j < 5; ++j) atomicAdd(g + (size_t)bg * 5 + j, fast_tanh(h2[j]));
        }
    }
    __syncthreads();

    if (lds_pool) {
        for (int i = tid; i < R * 5; i += BK_T) {
            float v = ((float*)gacc)[i];
            if (v != 0.0f) atomicAdd(g + (size_t)bmin * 5 + i, v);
        }
    }
}

// ---- graph head ----
__global__ __launch_bounds__(256) void graph_kernel(
    const float* __restrict__ g,
    const float* __restrict__ W3, const float* __restrict__ b3,
    const float* __restrict__ W4, const float* __restrict__ b4,
    float* __restrict__ out)
{
    int i = blockIdx.x * 256 + threadIdx.x;
    if (i >= N_GRAPHS) return;
    float t[5];
    #pragma unroll
    for (int j = 0; j < 5; ++j) t[j] = b3[j];
    #pragma unroll
    for (int k = 0; k < 5; ++k) {
        float gk = g[(size_t)i * 5 + k];
        #pragma unroll
        for (int j = 0; j < 5; ++j) t[j] = fmaf(gk, W3[k*5 + j], t[j]);
    }
    float o = b4[0];
    #pragma unroll
    for (int k = 0; k < 5; ++k) o = fmaf(fast_tanh(t[k]), W4[k], o);
    out[i] = o;
}

// ============================================================
//             LEGACY PATH (ws < 107 MB)
// ============================================================
__global__ __launch_bounds__(1024) void scatter_legacy_kernel(
    const int* __restrict__ ei, uint2* __restrict__ sorted,
    unsigned* __restrict__ cursor, unsigned* __restrict__ ovf_cnt,
    uint2* __restrict__ ovf)
{
    __shared__ unsigned hist[NB];
    __shared__ unsigned lbase[NB];
    const int tid = threadIdx.x;
    const int e0  = blockIdx.x * L_BLK_E;

    for (int b = tid; b < NB; b += 1024) hist[b] = 0u;
    __syncthreads();

    int dcache[L_BLK_E / 1024];
    #pragma unroll
    for (int k = 0; k < L_BLK_E / 1024; ++k) {
        int e = e0 + k * 1024 + tid;
        int d = (e < N_EDGES) ? __builtin_nontemporal_load(ei + N_EDGES + e) : -1;
        dcache[k] = d;
        if (d >= 0) atomicAdd(&hist[d >> 7], 1u);
    }
    __syncthreads();
    for (int b = tid; b < NB; b += 1024) {
        unsigned c = hist[b];
        lbase[b] = c ? atomicAdd(cursor + b, c) : 0u;
        hist[b] = 0u;
    }
    __syncthreads();
    #pragma unroll
    for (int k = 0; k < L_BLK_E / 1024; ++k) {
        int d = dcache[k];
        if (d < 0) continue;
        int e = e0 + k * 1024 + tid;
        int s = __builtin_nontemporal_load(ei + e);
        int bk = d >> 7;
        unsigned pos = lbase[bk] + atomicAdd(&hist[bk], 1u);
        uint2 ent;
        ent.x = (unsigned)e | ((unsigned)bk << 22);
        ent.y = (unsigned)s | ((unsigned)(d & 127) << 17);
        if (pos < L_CAP) sorted[(size_t)bk * L_CAP + pos] = ent;
        else {
            unsigned op = atomicAdd(ovf_cnt, 1u);
            if (op < L_OVF_CAP) ovf[op] = ent;
        }
    }
}

__device__ __forceinline__ void legacy_accum_edge(
    uint2 ent, const float* __restrict__ node_attr, const float* __restrict__ edge_attr,
    const float* __restrict__ Wm, const float* __restrict__ bm, float (*acc)[10])
{
    unsigned eid = ent.x & 0x3FFFFFu;
    unsigned src = ent.y & 0x1FFFFu;
    unsigned dl  = (ent.y >> 17) & 0x7Fu;
    float in[32];
    const f32x4* na = reinterpret_cast<const f32x4*>(node_attr + (size_t)src * 16);
    const f32x4* ea = reinterpret_cast<const f32x4*>(edge_attr + (size_t)eid * 16);
    #pragma unroll
    for (int q = 0; q < 4; ++q) { f32x4 v = na[q];
        in[q*4]=v.x; in[q*4+1]=v.y; in[q*4+2]=v.z; in[q*4+3]=v.w; }
    #pragma unroll
    for (int q = 0; q < 4; ++q) { f32x4 v = __builtin_nontemporal_load(ea + q);
        in[16+q*4]=v.x; in[16+q*4+1]=v.y; in[16+q*4+2]=v.z; in[16+q*4+3]=v.w; }
    float m[10];
    #pragma unroll
    for (int j = 0; j < 10; ++j) m[j] = bm[j];
    #pragma unroll
    for (int i = 0; i < 32; ++i) {
        float xi = in[i];
        #pragma unroll
        for (int j = 0; j < 10; ++j) m[j] = fmaf(xi, Wm[i*10 + j], m[j]);
    }
    #pragma unroll
    for (int j = 0; j < 10; ++j) atomicAdd(&acc[dl][j], fast_tanh(m[j]));
}

__global__ __launch_bounds__(1024, 8) void bucket_legacy_kernel(
    const uint2* __restrict__ sorted, const unsigned* __restrict__ cursor,
    const unsigned* __restrict__ ovf_cnt, const uint2* __restrict__ ovf,
    const float* __restrict__ node_attr, const float* __restrict__ edge_attr,
    const int* __restrict__ batch,
    const float* __restrict__ Wm, const float* __restrict__ bm,
    const float* __restrict__ W1, const float* __restrict__ b1,
    const float* __restrict__ W2, const float* __restrict__ b2,
    float* __restrict__ g)
{
    __shared__ float acc[NPB][10];
    __shared__ float gacc[64][5];
    __shared__ int bse[2];
    const int tid = threadIdx.x;
    const int b   = blockIdx.x;

    for (int i = tid; i < NPB * 10; i += 1024) ((float*)acc)[i] = 0.0f;
    __syncthreads();

    const unsigned cnt = min(cursor[b], (unsigned)L_CAP);
    const uint2* basep = sorted + (size_t)b * L_CAP;
    for (unsigned i = tid; i < cnt; i += 1024)
        legacy_accum_edge(basep[i], node_attr, edge_attr, Wm, bm, acc);
    __syncthreads();

    unsigned L = min(*ovf_cnt, (unsigned)L_OVF_CAP);
    if (L) {
        for (unsigned i = tid; i < L; i += 1024) {
            uint2 ent = ovf[i];
            if ((ent.x >> 22) == (unsigned)b)
                legacy_accum_edge(ent, node_attr, edge_attr, Wm, bm, acc);
        }
        __syncthreads();
    }

    if (tid == 0) {
        int nfirst = b * NPB;
        int nlast  = min(nfirst + NPB - 1, N_NODES - 1);
        bse[0] = batch[nfirst]; bse[1] = batch[nlast];
    }
    __syncthreads();
    const int bmin = bse[0];
    const int R    = bse[1] - bse[0] + 1;
    const bool lds_pool = (R <= 64);
    if (lds_pool)
        for (int i = tid; i < R * 5; i += 1024) ((float*)gacc)[i] = 0.0f;
    __syncthreads();

    const int n = b * NPB + tid;
    if (tid < NPB && n < N_NODES) {
        float h1[10];
        #pragma unroll
        for (int j = 0; j < 10; ++j) h1[j] = b1[j];
        #pragma unroll
        for (int i = 0; i < 10; ++i) {
            float xi = acc[tid][i];
            #pragma unroll
            for (int j = 0; j < 10; ++j) h1[j] = fmaf(xi, W1[i*10 + j], h1[j]);
        }
        #pragma unroll
        for (int j = 0; j < 10; ++j) h1[j] = fast_tanh(h1[j]);
        float h2[5];
        #pragma unroll
        for (int j = 0; j < 5; ++j) h2[j] = b2[j];
        #pragma unroll
        for (int i = 0; i < 10; ++i) {
            float xi = h1[i];
            #pragma unroll
            for (int j = 0; j < 5; ++j) h2[j] = fmaf(xi, W2[i*5 + j], h2[j]);
        }
        const int bg = batch[n];
        if (lds_pool) {
            #pragma unroll
            for (int j = 0; j < 5; ++j) atomicAdd(&gacc[bg - bmin][j], fast_tanh(h2[j]));
        } else {
            #pragma unroll
            for (int j = 0; j < 5; ++j) atomicAdd(g + (size_t)bg * 5 + j, fast_tanh(h2[j]));
        }
    }
    __syncthreads();
    if (lds_pool) {
        for (int i = tid; i < R * 5; i += 1024) {
            float v = ((float*)gacc)[i];
            if (v != 0.0f) atomicAdd(g + (size_t)bmin * 5 + i, v);
        }
    }
}

// ============================================================
extern "C" void kernel_launch(void* const* d_in, const int* in_sizes, int n_in,
                              void* d_out, int out_size, void* d_ws, size_t ws_size,
                              hipStream_t stream) {
    const int*   ei        = (const int*)  d_in[0];
    const float* node_attr = (const float*)d_in[1];
    const float* edge_attr = (const float*)d_in[2];
    const int*   batch     = (const int*)  d_in[3];
    const float* Wm = (const float*)d_in[4];
    const float* bm = (const float*)d_in[5];
    const float* W1 = (const float*)d_in[6];
    const float* b1 = (const float*)d_in[7];
    const float* W2 = (const float*)d_in[8];
    const float* b2 = (const float*)d_in[9];
    const float* W3 = (const float*)d_in[10];
    const float* b3 = (const float*)d_in[11];
    const float* W4 = (const float*)d_in[12];
    const float* b4 = (const float*)d_in[13];
    float* out = (float*)d_out;
    char* ws = (char*)d_ws;

    if (ws_size >= WS_FAT) {
        unsigned* hist   = (unsigned*)(ws + HIST_OFF);
        unsigned* base   = (unsigned*)(ws + BASE_OFF);
        unsigned* cursor = (unsigned*)(ws + CUR_OFF);
        float*    g      = (float*)   (ws + G_OFF);
        unsigned* P      = (unsigned*)(ws + P_OFF);
        unsigned* ent    = (unsigned*)(ws + ENT_OFF);

        (void)hipMemsetAsync(ws, 0, ZERO_BYTES, stream);
        hist_kernel<<<256, 1024, 0, stream>>>(ei, hist);
        nodeproj_kernel<<<(N_NODES + 255) / 256, 256, 0, stream>>>(node_attr, Wm, P);
        scan_kernel<<<1, 1024, 0, stream>>>(hist, base, cursor);
        scatter_msg_kernel<<<S_GRID, S_T, 0, stream>>>(ei, edge_attr, P, Wm, bm, cursor, ent);
        bucket_sort_kernel<<<NB, BK_T, 0, stream>>>(ent, base, batch, W1, b1, W2, b2, g);
        graph_kernel<<<(N_GRAPHS + 255) / 256, 256, 0, stream>>>(g, W3, b3, W4, b4, out);
    } else if (ws_size >= L_WS_NEED) {
        unsigned* cursor  = (unsigned*)(ws + L_CUR_OFF);
        unsigned* ovf_cnt = (unsigned*)(ws + L_OVFC_OFF);
        float*    g       = (float*)   (ws + L_G_OFF);
        uint2*    ovf     = (uint2*)   (ws + L_OVF_OFF);
        uint2*    sorted  = (uint2*)   (ws + L_SORT_OFF);

        (void)hipMemsetAsync(ws, 0, L_ZERO_BYTES, stream);
        scatter_legacy_kernel<<<L_S1_GRID, 1024, 0, stream>>>(ei, sorted, cursor, ovf_cnt, ovf);
        bucket_legacy_kernel<<<NB, 1024, 0, stream>>>(sorted, cursor, ovf_cnt, ovf,
                                                      node_attr, edge_attr, batch,
                                                      Wm, bm, W1, b1, W2, b2, g);
        graph_kernel<<<(N_GRAPHS + 255) / 256, 256, 0, stream>>>(g, W3, b3, W4, b4, out);
    }
}

// Round 13
// 230.830 us; speedup vs baseline: 1.0560x; 1.0560x over previous
//
#include <hip/hip_runtime.h>

#define N_NODES  100000
#define N_EDGES  3200000
#define N_GRAPHS 1000

#define NPB      128                                  // nodes per bucket (pow2)
#define NB       782                                  // ceil(N_NODES/NPB)
#define CAPL     4608                                 // slots/bucket: mean 4092 + 8 sigma
#define OVF_CAP  16384

typedef float    f32x4 __attribute__((ext_vector_type(4)));
typedef unsigned u32x4 __attribute__((ext_vector_type(4)));

// ---------------- fat-path ws layout (bytes) ----------------
#define CUR_OFF    0                                  // u32 cursor[NB]
#define OVFC_OFF   4096                               // u32 ovf_cnt
#define G_OFF      4352                               // f32 g[5000] -> ends 24352
#define ZERO_BYTES 24576                              // memset [0, ZERO_BYTES)
#define OVF_OFF    24576                              // 32B ovf entries [16384] -> ends 548864
#define P_OFF      548864                             // u32 P[N_NODES][8] f16 = 3.2 MB
#define ENT_OFF    3748864                            // 32B entries [NB*CAPL]
#define WS_FAT     (ENT_OFF + (size_t)NB * CAPL * 32) // ~119 MB

// scatter config: 512 blocks (2/CU), 6250 edges each (512*6250 = 3.2M exactly)
#define S_T      1024
#define S_GRID   512
#define S_E      6250
#define S_K      7                                    // S_E == S_K*S_T - 918 pad handled by exact split
#define BK_T     1024

// ---------------- legacy (round-5) ws layout ----------------
#define L_CAP      4500
#define L_OVF_CAP  16384
#define L_BLK_E    8192
#define L_S1_GRID  ((N_EDGES + L_BLK_E - 1) / L_BLK_E)
#define L_CUR_OFF    0
#define L_OVFC_OFF   4096
#define L_G_OFF      4352
#define L_ZERO_BYTES 24576
#define L_OVF_OFF    24576
#define L_SORT_OFF   163840
#define L_WS_NEED    (L_SORT_OFF + (size_t)NB * L_CAP * 8)

__device__ __forceinline__ float fast_tanh(float x) {
    float e = __expf(2.0f * x);
    return 1.0f - 2.0f * __builtin_amdgcn_rcpf(e + 1.0f);
}

__device__ __forceinline__ unsigned pkh(float a, float b) {
    union { _Float16 h[2]; unsigned u; } c;
    c.h[0] = (_Float16)a; c.h[1] = (_Float16)b;
    return c.u;
}
__device__ __forceinline__ void upkh(unsigned u, float& a, float& b) {
    union { unsigned u; _Float16 h[2]; } c;
    c.u = u;
    a = (float)c.h[0]; b = (float)c.h[1];
}

// ============================================================
//                      FAT PATH
// ============================================================

// ---- node projection: P[n] = f16-packed node_attr[n] @ Wm rows 0..15 ----
__global__ __launch_bounds__(256) void nodeproj_kernel(
    const float* __restrict__ node_attr, const float* __restrict__ Wm,
    unsigned* __restrict__ P)
{
    int n = blockIdx.x * 256 + threadIdx.x;
    if (n >= N_NODES) return;
    float r[16];
    const f32x4* na = reinterpret_cast<const f32x4*>(node_attr + (size_t)n * 16);
    #pragma unroll
    for (int q = 0; q < 4; ++q) {
        f32x4 v = na[q];
        r[q*4+0] = v.x; r[q*4+1] = v.y; r[q*4+2] = v.z; r[q*4+3] = v.w;
    }
    float p[10];
    #pragma unroll
    for (int j = 0; j < 10; ++j) p[j] = 0.0f;
    #pragma unroll
    for (int i = 0; i < 16; ++i) {
        float xi = r[i];
        #pragma unroll
        for (int j = 0; j < 10; ++j) p[j] = fmaf(xi, Wm[i*10 + j], p[j]);
    }
    u32x4* pd = reinterpret_cast<u32x4*>(P + (size_t)n * 8);
    u32x4 w0 = {pkh(p[0],p[1]), pkh(p[2],p[3]), pkh(p[4],p[5]), pkh(p[6],p[7])};
    u32x4 w1 = {pkh(p[8],p[9]), 0u, 0u, 0u};
    pd[0] = w0; pd[1] = w1;
}

// ---- scatter: fixed CAPL bucket regions (no hist/scan); src loaded in count
//      pass -> P gather 2 iterations deep; edge_attr 1-ahead; 32B f16 entries ----
__global__ __launch_bounds__(S_T, 4) void scatter_msg_kernel(
    const int* __restrict__ ei, const float* __restrict__ edge_attr,
    const unsigned* __restrict__ P,
    const float* __restrict__ Wm, const float* __restrict__ bm,
    unsigned* __restrict__ cursor, unsigned* __restrict__ entries,
    unsigned* __restrict__ ovf_cnt, unsigned* __restrict__ ovf)
{
    __shared__ unsigned lh[NB];
    __shared__ unsigned lb[NB];
    const int tid = threadIdx.x;
    const int e0  = blockIdx.x * S_E;
    const int e1  = e0 + S_E;                          // exact (512*6250 = E)

    for (int b = tid; b < NB; b += S_T) lh[b] = 0u;
    __syncthreads();

    // count pass: dst rank via LDS atomic return; src loaded here too
    int dch[S_K], sch[S_K];
    unsigned rch[S_K];
    #pragma unroll
    for (int k = 0; k < S_K; ++k) {
        int e = e0 + k * S_T + tid;
        bool v = (e < e1);
        int ec = v ? e : (e1 - 1);
        int d = __builtin_nontemporal_load(ei + N_EDGES + ec);
        int s = __builtin_nontemporal_load(ei + ec);
        dch[k] = v ? d : -1;
        sch[k] = s;
        rch[k] = v ? atomicAdd(&lh[d >> 7], 1u) : 0u;
    }
    __syncthreads();

    for (int b = tid; b < NB; b += S_T) {
        unsigned c = lh[b];
        lb[b] = c ? atomicAdd(cursor + b, c) : 0u;     // per-bucket cursor from 0
    }
    __syncthreads();

    // packed slot: fit -> (global_slot<<7)|dl ; overflow -> flag|(bk<<7)|dl
    unsigned mch[S_K];
    #pragma unroll
    for (int k = 0; k < S_K; ++k) {
        int d = dch[k];
        if (d >= 0) {
            unsigned bk = (unsigned)(d >> 7);
            unsigned pl = lb[bk] + rch[k];
            mch[k] = (pl < CAPL) ? ((((unsigned)bk * CAPL + pl) << 7) | (unsigned)(d & 127))
                                 : (0x80000000u | (bk << 7) | (unsigned)(d & 127));
        } else {
            mch[k] = 0xFFFFFFFFu;                      // invalid (tail)
        }
    }

    const int eBase = e0 + tid;
    const int last  = e1 - 1;
    #define ECL(x) ((x) > last ? last : (x))

    // ---- pipeline prologue: ea(0); P(0), P(1) (src already in regs) ----
    f32x4 rA0, rA1, rA2, rA3;
    {
        const f32x4* ea = reinterpret_cast<const f32x4*>(edge_attr + (size_t)ECL(eBase) * 16);
        rA0 = __builtin_nontemporal_load(ea + 0);
        rA1 = __builtin_nontemporal_load(ea + 1);
        rA2 = __builtin_nontemporal_load(ea + 2);
        rA3 = __builtin_nontemporal_load(ea + 3);
    }
    u32x4 pA; unsigned pA4;
    {
        const u32x4* pp = reinterpret_cast<const u32x4*>(P + (size_t)sch[0] * 8);
        pA = pp[0]; pA4 = P[(size_t)sch[0] * 8 + 4];
    }
    u32x4 pB; unsigned pB4;
    {
        const u32x4* pp = reinterpret_cast<const u32x4*>(P + (size_t)sch[1] * 8);
        pB = pp[0]; pB4 = P[(size_t)sch[1] * 8 + 4];
    }

    #pragma unroll
    for (int k = 0; k < S_K; ++k) {
        const int e = eBase + k * S_T;

        // issue edge_attr k+1
        f32x4 rB0 = rA0, rB1 = rA1, rB2 = rA2, rB3 = rA3;
        if (k + 1 < S_K) {
            const f32x4* ea = reinterpret_cast<const f32x4*>(edge_attr + (size_t)ECL(e + S_T) * 16);
            rB0 = __builtin_nontemporal_load(ea + 0);
            rB1 = __builtin_nontemporal_load(ea + 1);
            rB2 = __builtin_nontemporal_load(ea + 2);
            rB3 = __builtin_nontemporal_load(ea + 3);
        }
        // issue P k+2 (2 iterations of latency cover; src in registers)
        u32x4 pC = pB; unsigned pC4 = pB4;
        if (k + 2 < S_K) {
            const u32x4* pp = reinterpret_cast<const u32x4*>(P + (size_t)sch[k + 2] * 8);
            pC = pp[0]; pC4 = P[(size_t)sch[k + 2] * 8 + 4];
        }

        const unsigned mc = mch[k];
        if (mc != 0xFFFFFFFFu) {
            float r[16];
            r[0]=rA0.x; r[1]=rA0.y; r[2]=rA0.z; r[3]=rA0.w;
            r[4]=rA1.x; r[5]=rA1.y; r[6]=rA1.z; r[7]=rA1.w;
            r[8]=rA2.x; r[9]=rA2.y; r[10]=rA2.z; r[11]=rA2.w;
            r[12]=rA3.x; r[13]=rA3.y; r[14]=rA3.z; r[15]=rA3.w;

            float B[10];
            #pragma unroll
            for (int j = 0; j < 10; ++j) B[j] = bm[j];
            #pragma unroll
            for (int i = 0; i < 16; ++i) {
                float xi = r[i];
                #pragma unroll
                for (int j = 0; j < 10; ++j) B[j] = fmaf(xi, Wm[(16 + i)*10 + j], B[j]);
            }
            float Pv[10];
            upkh(pA.x, Pv[0], Pv[1]);
            upkh(pA.y, Pv[2], Pv[3]);
            upkh(pA.z, Pv[4], Pv[5]);
            upkh(pA.w, Pv[6], Pv[7]);
            upkh(pA4,  Pv[8], Pv[9]);
            float m[10];
            #pragma unroll
            for (int j = 0; j < 10; ++j) m[j] = fast_tanh(B[j] + Pv[j]);

            u32x4 w0 = {pkh(m[0],m[1]), pkh(m[2],m[3]), pkh(m[4],m[5]), pkh(m[6],m[7])};
            if (!(mc & 0x80000000u)) {
                unsigned pos = mc >> 7;
                u32x4* ep = reinterpret_cast<u32x4*>(entries + (size_t)pos * 8);
                u32x4 w1 = {pkh(m[8],m[9]), mc & 127u, 0u, 0u};
                ep[0] = w0;
                ep[1] = w1;
            } else {                                   // overflow spill (p ~ 1e-15)
                unsigned op = atomicAdd(ovf_cnt, 1u);
                if (op < OVF_CAP) {
                    u32x4* ep = reinterpret_cast<u32x4*>(ovf + (size_t)op * 8);
                    u32x4 w1 = {pkh(m[8],m[9]), mc & 0x7FFFFFFFu, 0u, 0u}; // (bk<<7)|dl
                    ep[0] = w0;
                    ep[1] = w1;
                }
            }
        }

        // rotate pipeline
        rA0 = rB0; rA1 = rB1; rA2 = rB2; rA3 = rB3;
        pA = pB; pA4 = pB4;
        pB = pC; pB4 = pC4;
    }
    #undef ECL
}

// ---- per-bucket: counting-sort by dst-local, owner-computes register
//      segment-sum, fused node MLP + graph pooling ----
__global__ __launch_bounds__(BK_T, 8) void bucket_sort_kernel(
    const unsigned* __restrict__ entries, const unsigned* __restrict__ cursor,
    const unsigned* __restrict__ ovf_cnt, const unsigned* __restrict__ ovf,
    const int* __restrict__ batch,
    const float* __restrict__ W1, const float* __restrict__ b1,
    const float* __restrict__ W2, const float* __restrict__ b2,
    float* __restrict__ g)
{
    __shared__ unsigned seq[CAPL];                     // dl per local entry
    __shared__ unsigned ord[CAPL];                     // dl-sorted local idx
    __shared__ unsigned h[NPB], st[NPB], c2[NPB];
    __shared__ float gacc[64][5];
    __shared__ int bse[2];
    const int tid = threadIdx.x;
    const int b   = blockIdx.x;
    const size_t   lo  = (size_t)b * CAPL;
    const unsigned cnt = min(cursor[b], (unsigned)CAPL);

    if (tid < NPB) h[tid] = 0u;
    __syncthreads();

    // phase 1: read meta, build per-node histogram + seq
    for (unsigned i = tid; i < cnt; i += BK_T) {
        unsigned dl = entries[(lo + i) * 8 + 5] & 127u;
        seq[i] = dl;
        atomicAdd(&h[dl], 1u);
    }
    __syncthreads();

    // exclusive scan of h -> st, c2
    if (tid < NPB) st[tid] = h[tid];
    __syncthreads();
    #pragma unroll
    for (int off = 1; off < NPB; off <<= 1) {
        unsigned t = 0;
        if (tid < NPB && tid >= off) t = st[tid - off];
        __syncthreads();
        if (tid < NPB) st[tid] += t;
        __syncthreads();
    }
    if (tid < NPB) { unsigned e = st[tid] - h[tid]; st[tid] = e; c2[tid] = e; }
    __syncthreads();

    // phase 2: scatter indices into dl-sorted order
    for (unsigned i = tid; i < cnt; i += BK_T) {
        unsigned pos = atomicAdd(&c2[seq[i]], 1u);
        ord[pos] = i;
    }
    __syncthreads();

    // graph range of this block's nodes (batch sorted)
    if (tid == 0) {
        int nfirst = b * NPB;
        int nlast  = min(nfirst + NPB - 1, N_NODES - 1);
        bse[0] = batch[nfirst];
        bse[1] = batch[nlast];
    }
    __syncthreads();
    const int bmin = bse[0];
    const int R    = bse[1] - bmin + 1;
    const bool lds_pool = (R <= 64);
    if (lds_pool)
        for (int i = tid; i < R * 5; i += BK_T) ((float*)gacc)[i] = 0.0f;
    __syncthreads();

    // phase 3: owner-computes — node dl = tid>>3, slice s = tid&7
    const int dl = tid >> 3, s = tid & 7;
    float a[10];
    #pragma unroll
    for (int j = 0; j < 10; ++j) a[j] = 0.0f;
    {
        const unsigned s0 = st[dl], c = h[dl];
        for (unsigned p = s; p < c; p += 8) {
            unsigned li = ord[s0 + p];
            const u32x4* ep = reinterpret_cast<const u32x4*>(entries + (lo + li) * 8);
            u32x4 v0 = ep[0];                          // L2-warm (phase-1 touch)
            u32x4 v1 = ep[1];
            float x0, x1;
            upkh(v0.x, x0, x1); a[0] += x0; a[1] += x1;
            upkh(v0.y, x0, x1); a[2] += x0; a[3] += x1;
            upkh(v0.z, x0, x1); a[4] += x0; a[5] += x1;
            upkh(v0.w, x0, x1); a[6] += x0; a[7] += x1;
            upkh(v1.x, x0, x1); a[8] += x0; a[9] += x1;
        }
    }
    #pragma unroll
    for (int msk = 4; msk >= 1; msk >>= 1) {
        #pragma unroll
        for (int j = 0; j < 10; ++j) a[j] += __shfl_xor(a[j], msk, 64);
    }

    // overflow entries (normally zero)
    unsigned L = min(*ovf_cnt, (unsigned)OVF_CAP);
    if (L) {
        for (unsigned i = 0; i < L; ++i) {
            const u32x4* ep = reinterpret_cast<const u32x4*>(ovf + (size_t)i * 8);
            u32x4 v0 = ep[0];
            u32x4 v1 = ep[1];
            unsigned meta = v1.y;                      // (bk<<7)|dl
            if ((int)(meta >> 7) == b && (int)(meta & 127u) == dl && s == 0) {
                float x0, x1;
                upkh(v0.x, x0, x1); a[0] += x0; a[1] += x1;
                upkh(v0.y, x0, x1); a[2] += x0; a[3] += x1;
                upkh(v0.z, x0, x1); a[4] += x0; a[5] += x1;
                upkh(v0.w, x0, x1); a[6] += x0; a[7] += x1;
                upkh(v1.x, x0, x1); a[8] += x0; a[9] += x1;
            }
        }
    }

    const int n = b * NPB + dl;
    if (s == 0 && n < N_NODES) {
        float h1[10];
        #pragma unroll
        for (int j = 0; j < 10; ++j) h1[j] = b1[j];
        #pragma unroll
        for (int i = 0; i < 10; ++i) {
            float xi = a[i];
            #pragma unroll
            for (int j = 0; j < 10; ++j) h1[j] = fmaf(xi, W1[i*10 + j], h1[j]);
        }
        #pragma unroll
        for (int j = 0; j < 10; ++j) h1[j] = fast_tanh(h1[j]);

        float h2[5];
        #pragma unroll
        for (int j = 0; j < 5; ++j) h2[j] = b2[j];
        #pragma unroll
        for (int i = 0; i < 10; ++i) {
            float xi = h1[i];
            #pragma unroll
            for (int j = 0; j < 5; ++j) h2[j] = fmaf(xi, W2[i*5 + j], h2[j]);
        }

        const int bg = batch[n];
        if (lds_pool) {
            #pragma unroll
            for (int j = 0; j < 5; ++j) atomicAdd(&gacc[bg - bmin][j], fast_tanh(h2[j]));
        } else {
            #pragma unroll
            for (int j = 0; j < 5; ++j) atomicAdd(g + (size_t)bg * 5 + j, fast_tanh(h2[j]));
        }
    }
    __syncthreads();

    if (lds_pool) {
        for (int i = tid; i < R * 5; i += BK_T) {
            float v = ((float*)gacc)[i];
            if (v != 0.0f) atomicAdd(g + (size_t)bmin * 5 + i, v);
        }
    }
}

// ---- graph head ----
__global__ __launch_bounds__(256) void graph_kernel(
    const float* __restrict__ g,
    const float* __restrict__ W3, const float* __restrict__ b3,
    const float* __restrict__ W4, const float* __restrict__ b4,
    float* __restrict__ out)
{
    int i = blockIdx.x * 256 + threadIdx.x;
    if (i >= N_GRAPHS) return;
    float t[5];
    #pragma unroll
    for (int j = 0; j < 5; ++j) t[j] = b3[j];
    #pragma unroll
    for (int k = 0; k < 5; ++k) {
        float gk = g[(size_t)i * 5 + k];
        #pragma unroll
        for (int j = 0; j < 5; ++j) t[j] = fmaf(gk, W3[k*5 + j], t[j]);
    }
    float o = b4[0];
    #pragma unroll
    for (int k = 0; k < 5; ++k) o = fmaf(fast_tanh(t[k]), W4[k], o);
    out[i] = o;
}

// ============================================================
//             LEGACY PATH (ws < 119 MB)
// ============================================================
__global__ __launch_bounds__(1024) void scatter_legacy_kernel(
    const int* __restrict__ ei, uint2* __restrict__ sorted,
    unsigned* __restrict__ cursor, unsigned* __restrict__ ovf_cnt,
    uint2* __restrict__ ovf)
{
    __shared__ unsigned hist[NB];
    __shared__ unsigned lbase[NB];
    const int tid = threadIdx.x;
    const int e0  = blockIdx.x * L_BLK_E;

    for (int b = tid; b < NB; b += 1024) hist[b] = 0u;
    __syncthreads();

    int dcache[L_BLK_E / 1024];
    #pragma unroll
    for (int k = 0; k < L_BLK_E / 1024; ++k) {
        int e = e0 + k * 1024 + tid;
        int d = (e < N_EDGES) ? __builtin_nontemporal_load(ei + N_EDGES + e) : -1;
        dcache[k] = d;
        if (d >= 0) atomicAdd(&hist[d >> 7], 1u);
    }
    __syncthreads();
    for (int b = tid; b < NB; b += 1024) {
        unsigned c = hist[b];
        lbase[b] = c ? atomicAdd(cursor + b, c) : 0u;
        hist[b] = 0u;
    }
    __syncthreads();
    #pragma unroll
    for (int k = 0; k < L_BLK_E / 1024; ++k) {
        int d = dcache[k];
        if (d < 0) continue;
        int e = e0 + k * 1024 + tid;
        int s = __builtin_nontemporal_load(ei + e);
        int bk = d >> 7;
        unsigned pos = lbase[bk] + atomicAdd(&hist[bk], 1u);
        uint2 ent;
        ent.x = (unsigned)e | ((unsigned)bk << 22);
        ent.y = (unsigned)s | ((unsigned)(d & 127) << 17);
        if (pos < L_CAP) sorted[(size_t)bk * L_CAP + pos] = ent;
        else {
            unsigned op = atomicAdd(ovf_cnt, 1u);
            if (op < L_OVF_CAP) ovf[op] = ent;
        }
    }
}

__device__ __forceinline__ void legacy_accum_edge(
    uint2 ent, const float* __restrict__ node_attr, const float* __restrict__ edge_attr,
    const float* __restrict__ Wm, const float* __restrict__ bm, float (*acc)[10])
{
    unsigned eid = ent.x & 0x3FFFFFu;
    unsigned src = ent.y & 0x1FFFFu;
    unsigned dl  = (ent.y >> 17) & 0x7Fu;
    float in[32];
    const f32x4* na = reinterpret_cast<const f32x4*>(node_attr + (size_t)src * 16);
    const f32x4* ea = reinterpret_cast<const f32x4*>(edge_attr + (size_t)eid * 16);
    #pragma unroll
    for (int q = 0; q < 4; ++q) { f32x4 v = na[q];
        in[q*4]=v.x; in[q*4+1]=v.y; in[q*4+2]=v.z; in[q*4+3]=v.w; }
    #pragma unroll
    for (int q = 0; q < 4; ++q) { f32x4 v = __builtin_nontemporal_load(ea + q);
        in[16+q*4]=v.x; in[16+q*4+1]=v.y; in[16+q*4+2]=v.z; in[16+q*4+3]=v.w; }
    float m[10];
    #pragma unroll
    for (int j = 0; j < 10; ++j) m[j] = bm[j];
    #pragma unroll
    for (int i = 0; i < 32; ++i) {
        float xi = in[i];
        #pragma unroll
        for (int j = 0; j < 10; ++j) m[j] = fmaf(xi, Wm[i*10 + j], m[j]);
    }
    #pragma unroll
    for (int j = 0; j < 10; ++j) atomicAdd(&acc[dl][j], fast_tanh(m[j]));
}

__global__ __launch_bounds__(1024, 8) void bucket_legacy_kernel(
    const uint2* __restrict__ sorted, const unsigned* __restrict__ cursor,
    const unsigned* __restrict__ ovf_cnt, const uint2* __restrict__ ovf,
    const float* __restrict__ node_attr, const float* __restrict__ edge_attr,
    const int* __restrict__ batch,
    const float* __restrict__ Wm, const float* __restrict__ bm,
    const float* __restrict__ W1, const float* __restrict__ b1,
    const float* __restrict__ W2, const float* __restrict__ b2,
    float* __restrict__ g)
{
    __shared__ float acc[NPB][10];
    __shared__ float gacc[64][5];
    __shared__ int bse[2];
    const int tid = threadIdx.x;
    const int b   = blockIdx.x;

    for (int i = tid; i < NPB * 10; i += 1024) ((float*)acc)[i] = 0.0f;
    __syncthreads();

    const unsigned cnt = min(cursor[b], (unsigned)L_CAP);
    const uint2* basep = sorted + (size_t)b * L_CAP;
    for (unsigned i = tid; i < cnt; i += 1024)
        legacy_accum_edge(basep[i], node_attr, edge_attr, Wm, bm, acc);
    __syncthreads();

    unsigned L = min(*ovf_cnt, (unsigned)L_OVF_CAP);
    if (L) {
        for (unsigned i = tid; i < L; i += 1024) {
            uint2 ent = ovf[i];
            if ((ent.x >> 22) == (unsigned)b)
                legacy_accum_edge(ent, node_attr, edge_attr, Wm, bm, acc);
        }
        __syncthreads();
    }

    if (tid == 0) {
        int nfirst = b * NPB;
        int nlast  = min(nfirst + NPB - 1, N_NODES - 1);
        bse[0] = batch[nfirst]; bse[1] = batch[nlast];
    }
    __syncthreads();
    const int bmin = bse[0];
    const int R    = bse[1] - bse[0] + 1;
    const bool lds_pool = (R <= 64);
    if (lds_pool)
        for (int i = tid; i < R * 5; i += 1024) ((float*)gacc)[i] = 0.0f;
    __syncthreads();

    const int n = b * NPB + tid;
    if (tid < NPB && n < N_NODES) {
        float h1[10];
        #pragma unroll
        for (int j = 0; j < 10; ++j) h1[j] = b1[j];
        #pragma unroll
        for (int i = 0; i < 10; ++i) {
            float xi = acc[tid][i];
            #pragma unroll
            for (int j = 0; j < 10; ++j) h1[j] = fmaf(xi, W1[i*10 + j], h1[j]);
        }
        #pragma unroll
        for (int j = 0; j < 10; ++j) h1[j] = fast_tanh(h1[j]);
        float h2[5];
        #pragma unroll
        for (int j = 0; j < 5; ++j) h2[j] = b2[j];
        #pragma unroll
        for (int i = 0; i < 10; ++i) {
            float xi = h1[i];
            #pragma unroll
            for (int j = 0; j < 5; ++j) h2[j] = fmaf(xi, W2[i*5 + j], h2[j]);
        }
        const int bg = batch[n];
        if (lds_pool) {
            #pragma unroll
            for (int j = 0; j < 5; ++j) atomicAdd(&gacc[bg - bmin][j], fast_tanh(h2[j]));
        } else {
            #pragma unroll
            for (int j = 0; j < 5; ++j) atomicAdd(g + (size_t)bg * 5 + j, fast_tanh(h2[j]));
        }
    }
    __syncthreads();
    if (lds_pool) {
        for (int i = tid; i < R * 5; i += 1024) {
            float v = ((float*)gacc)[i];
            if (v != 0.0f) atomicAdd(g + (size_t)bmin * 5 + i, v);
        }
    }
}

// ============================================================
extern "C" void kernel_launch(void* const* d_in, const int* in_sizes, int n_in,
                              void* d_out, int out_size, void* d_ws, size_t ws_size,
                              hipStream_t stream) {
    const int*   ei        = (const int*)  d_in[0];
    const float* node_attr = (const float*)d_in[1];
    const float* edge_attr = (const float*)d_in[2];
    const int*   batch     = (const int*)  d_in[3];
    const float* Wm = (const float*)d_in[4];
    const float* bm = (const float*)d_in[5];
    const float* W1 = (const float*)d_in[6];
    const float* b1 = (const float*)d_in[7];
    const float* W2 = (const float*)d_in[8];
    const float* b2 = (const float*)d_in[9];
    const float* W3 = (const float*)d_in[10];
    const float* b3 = (const float*)d_in[11];
    const float* W4 = (const float*)d_in[12];
    const float* b4 = (const float*)d_in[13];
    float* out = (float*)d_out;
    char* ws = (char*)d_ws;

    if (ws_size >= WS_FAT) {
        unsigned* cursor  = (unsigned*)(ws + CUR_OFF);
        unsigned* ovf_cnt = (unsigned*)(ws + OVFC_OFF);
        float*    g       = (float*)   (ws + G_OFF);
        unsigned* ovf     = (unsigned*)(ws + OVF_OFF);
        unsigned* P       = (unsigned*)(ws + P_OFF);
        unsigned* ent     = (unsigned*)(ws + ENT_OFF);

        (void)hipMemsetAsync(ws, 0, ZERO_BYTES, stream);
        nodeproj_kernel<<<(N_NODES + 255) / 256, 256, 0, stream>>>(node_attr, Wm, P);
        scatter_msg_kernel<<<S_GRID, S_T, 0, stream>>>(ei, edge_attr, P, Wm, bm,
                                                       cursor, ent, ovf_cnt, ovf);
        bucket_sort_kernel<<<NB, BK_T, 0, stream>>>(ent, cursor, ovf_cnt, ovf,
                                                    batch, W1, b1, W2, b2, g);
        graph_kernel<<<(N_GRAPHS + 255) / 256, 256, 0, stream>>>(g, W3, b3, W4, b4, out);
    } else if (ws_size >= L_WS_NEED) {
        unsigned* cursor  = (unsigned*)(ws + L_CUR_OFF);
        unsigned* ovf_cnt = (unsigned*)(ws + L_OVFC_OFF);
        float*    g       = (float*)   (ws + L_G_OFF);
        uint2*    ovf     = (uint2*)   (ws + L_OVF_OFF);
        uint2*    sorted  = (uint2*)   (ws + L_SORT_OFF);

        (void)hipMemsetAsync(ws, 0, L_ZERO_BYTES, stream);
        scatter_legacy_kernel<<<L_S1_GRID, 1024, 0, stream>>>(ei, sorted, cursor, ovf_cnt, ovf);
        bucket_legacy_kernel<<<NB, 1024, 0, stream>>>(sorted, cursor, ovf_cnt, ovf,
                                                      node_attr, edge_attr, batch,
                                                      Wm, bm, W1, b1, W2, b2, g);
        graph_kernel<<<(N_GRAPHS + 255) / 256, 256, 0, stream>>>(g, W3, b3, W4, b4, out);
    }
}